// Round 2
// baseline (12.646 us; speedup 1.0000x reference)
//
#include <hip/hip_runtime.h>

#define NH 32
#define DIM 128
#define NR 16
#define MN 17   // only the top-left 17x17 block is non-identity

// All rotations are (0, r+1), r=0..15: row 0 accumulates; row j=r+1 is
// finalized at step r (it is still e_{r+1} when touched). Rows/cols >= 17
// are identity. No LDS, no barriers: identity stores issue immediately;
// only threads intersecting the 17x17 block replay the recurrence.
__global__ __launch_bounds__(256) void givens_rotation_kernel(
    const float* __restrict__ thetas,  // [NH][NR] f32
    float* __restrict__ out)           // [NH][DIM][DIM] f32
{
    const int head  = blockIdx.x >> 3;   // 32 heads
    const int chunk = blockIdx.x & 7;    // 8 row-chunks of 16 rows
    const int tid   = threadIdx.x;

    float* outh = out + (size_t)head * DIM * DIM;
    const int row_base = chunk * 16;
    const float* th = thetas + head * NR;   // wave-uniform base

    #pragma unroll
    for (int it = 0; it < 2; ++it) {
        const int idx = it * 256 + tid;        // float4 index within 16x128 slab
        const int row = row_base + (idx >> 5); // 32 float4 per row
        const int c4  = (idx & 31) * 4;

        float vals[4];
        if (row < MN && c4 < MN) {
            // Replay the 16-step scan for columns c4..c4+3 of this row.
            float row0[4];
            #pragma unroll
            for (int k = 0; k < 4; ++k) row0[k] = (c4 + k == 0) ? 1.0f : 0.0f;
            #pragma unroll
            for (int k = 0; k < 4; ++k) vals[k] = 0.0f;
            #pragma unroll
            for (int r = 0; r < NR; ++r) {
                const float t = th[r];         // uniform -> s_load
                const float c = cosf(t);
                const float s = sinf(t);
                #pragma unroll
                for (int k = 0; k < 4; ++k) {
                    const float qj = (c4 + k == r + 1) ? 1.0f : 0.0f;
                    if (row == r + 1) vals[k] = -s * row0[k] + c * qj;
                    row0[k] = c * row0[k] + s * qj;
                }
            }
            if (row == 0) {
                #pragma unroll
                for (int k = 0; k < 4; ++k) vals[k] = row0[k];
            }
        } else {
            #pragma unroll
            for (int k = 0; k < 4; ++k)
                vals[k] = (row == c4 + k) ? 1.0f : 0.0f;
        }

        float4 v;
        v.x = vals[0]; v.y = vals[1]; v.z = vals[2]; v.w = vals[3];
        *reinterpret_cast<float4*>(outh + row * DIM + c4) = v;
    }
}

extern "C" void kernel_launch(void* const* d_in, const int* in_sizes, int n_in,
                              void* d_out, int out_size, void* d_ws, size_t ws_size,
                              hipStream_t stream) {
    const float* thetas = (const float*)d_in[0];
    float* out = (float*)d_out;
    givens_rotation_kernel<<<dim3(NH * 8), dim3(256), 0, stream>>>(thetas, out);
}

// Round 3
// 9.543 us; speedup vs baseline: 1.3252x; 1.3252x over previous
//
#include <hip/hip_runtime.h>

#define NH 32
#define DIM 128
#define NR 16
#define MN 17   // only the top-left 17x17 block is non-identity

// All rotations are (0, r+1), r=0..15: row 0 accumulates; row j=r+1 is
// finalized at step r. Rows/cols >= 17 are identity.
// Chunks >= 2 (224/256 blocks): pure constant stores, no loads, no sync.
// Chunks 0/1: 4 overlapped float4 theta loads + hardware sin/cos, then
// a 16-step register recurrence for the <=5 special float4s per row.
__global__ __launch_bounds__(256) void givens_rotation_kernel(
    const float* __restrict__ thetas,  // [NH][NR] f32
    float* __restrict__ out)           // [NH][DIM][DIM] f32
{
    const int head  = blockIdx.x >> 3;   // 32 heads
    const int chunk = blockIdx.x & 7;    // 8 row-chunks of 16 rows
    const int tid   = threadIdx.x;

    float* outh = out + (size_t)head * DIM * DIM;
    const int row_base = chunk * 16;

    if (chunk >= 2) {
        // Pure identity slab: zero input dependency, fire-and-forget.
        #pragma unroll
        for (int it = 0; it < 2; ++it) {
            const int idx = it * 256 + tid;        // float4 index in 16x128 slab
            const int row = row_base + (idx >> 5); // 32 float4 per row
            const int c4  = (idx & 31) * 4;
            float4 v;
            v.x = (row == c4 + 0) ? 1.0f : 0.0f;
            v.y = (row == c4 + 1) ? 1.0f : 0.0f;
            v.z = (row == c4 + 2) ? 1.0f : 0.0f;
            v.w = (row == c4 + 3) ? 1.0f : 0.0f;
            *reinterpret_cast<float4*>(outh + row * DIM + c4) = v;
        }
        return;
    }

    // Rows 0..31 — intersects the 17x17 block. Load all thetas up front
    // as 4 independent float4 loads (uniform address -> scalar loads).
    const float4* th4 = reinterpret_cast<const float4*>(thetas + head * NR);
    const float4 t0 = th4[0], t1 = th4[1], t2 = th4[2], t3 = th4[3];
    const float th[NR] = {t0.x, t0.y, t0.z, t0.w, t1.x, t1.y, t1.z, t1.w,
                          t2.x, t2.y, t2.z, t2.w, t3.x, t3.y, t3.z, t3.w};
    float cs[NR], sn[NR];
    #pragma unroll
    for (int r = 0; r < NR; ++r) {
        sn[r] = __sinf(th[r]);   // hardware v_sin/v_cos: |theta| ~ 0.01,
        cs[r] = __cosf(th[r]);   // error ~1e-7 << 2e-2 threshold
    }

    #pragma unroll
    for (int it = 0; it < 2; ++it) {
        const int idx = it * 256 + tid;
        const int row = row_base + (idx >> 5);
        const int c4  = (idx & 31) * 4;

        float vals[4];
        if (row < MN && c4 < MN) {
            float row0[4];
            #pragma unroll
            for (int k = 0; k < 4; ++k) {
                row0[k] = (c4 + k == 0) ? 1.0f : 0.0f;
                vals[k] = 0.0f;
            }
            #pragma unroll
            for (int r = 0; r < NR; ++r) {
                const float c = cs[r], s = sn[r];
                #pragma unroll
                for (int k = 0; k < 4; ++k) {
                    const float qj = (c4 + k == r + 1) ? 1.0f : 0.0f;
                    if (row == r + 1) vals[k] = -s * row0[k] + c * qj;
                    row0[k] = c * row0[k] + s * qj;
                }
            }
            if (row == 0) {
                #pragma unroll
                for (int k = 0; k < 4; ++k) vals[k] = row0[k];
            }
        } else {
            #pragma unroll
            for (int k = 0; k < 4; ++k)
                vals[k] = (row == c4 + k) ? 1.0f : 0.0f;
        }

        float4 v;
        v.x = vals[0]; v.y = vals[1]; v.z = vals[2]; v.w = vals[3];
        *reinterpret_cast<float4*>(outh + row * DIM + c4) = v;
    }
}

extern "C" void kernel_launch(void* const* d_in, const int* in_sizes, int n_in,
                              void* d_out, int out_size, void* d_ws, size_t ws_size,
                              hipStream_t stream) {
    const float* thetas = (const float*)d_in[0];
    float* out = (float*)d_out;
    givens_rotation_kernel<<<dim3(NH * 8), dim3(256), 0, stream>>>(thetas, out);
}